// Round 1
// baseline (451.410 us; speedup 1.0000x reference)
//
#include <hip/hip_runtime.h>

// Problem constants (from reference): S=4096, B=32, F=512, H=512
constexpr int S = 4096;
constexpr int B = 32;
constexpr int F = 512;
constexpr int H = 512;

// ---------------------------------------------------------------------------
// Kernel 1: v[b,f] = sum_h hidden[b,h] * W_key[h,f]
// Grid: (F/64, B), block 64. W_key is 1 MB -> L2-resident after first pass.
// ---------------------------------------------------------------------------
__global__ void proj_kernel(const float* __restrict__ hidden,
                            const float* __restrict__ W_key,
                            float* __restrict__ v) {
    const int b = blockIdx.y;
    const int f = blockIdx.x * 64 + threadIdx.x;
    const float* hb = hidden + b * H;
    float acc = 0.f;
#pragma unroll 8
    for (int h = 0; h < H; ++h)
        acc = fmaf(hb[h], W_key[h * F + f], acc);
    v[b * F + f] = acc;
}

// ---------------------------------------------------------------------------
// Kernel 2: c[b] = sum_h b_key[h] * hidden[b,h]   (one wave per b)
// ---------------------------------------------------------------------------
__global__ void bias_dot_kernel(const float* __restrict__ hidden,
                                const float* __restrict__ b_key,
                                float* __restrict__ c) {
    const int b = blockIdx.x;
    const int lane = threadIdx.x;  // 64
    float acc = 0.f;
    for (int h = lane; h < H; h += 64)
        acc = fmaf(b_key[h], hidden[b * H + h], acc);
    for (int off = 32; off; off >>= 1) acc += __shfl_down(acc, off);
    if (lane == 0) c[b] = acc;
}

// ---------------------------------------------------------------------------
// Kernel 3: scores[s,b] = <features[s,b,:], v[b,:]> + c[b] - 99999*mask[s,b]
// One wave per (s,b) row. Row is 512 contiguous floats = 2 float4 per lane.
// Block 256 = 4 waves; grid = S*B/4 = 32768 blocks.
// ---------------------------------------------------------------------------
__global__ void score_kernel(const float* __restrict__ features,
                             const float* __restrict__ mask,
                             const float* __restrict__ v,
                             const float* __restrict__ c,
                             float* __restrict__ scores) {
    const int wid = (blockIdx.x * blockDim.x + threadIdx.x) >> 6;  // global wave
    const int lane = threadIdx.x & 63;
    const int s = wid / B;
    const int b = wid - s * B;

    const float4* row = reinterpret_cast<const float4*>(features + (size_t)wid * F);
    const float4* vb  = reinterpret_cast<const float4*>(v + b * F);

    float4 r0 = row[lane];
    float4 r1 = row[lane + 64];
    float4 v0 = vb[lane];
    float4 v1 = vb[lane + 64];

    float acc = r0.x * v0.x + r0.y * v0.y + r0.z * v0.z + r0.w * v0.w
              + r1.x * v1.x + r1.y * v1.y + r1.z * v1.z + r1.w * v1.w;

    for (int off = 32; off; off >>= 1) acc += __shfl_down(acc, off);

    if (lane == 0)
        scores[wid] = acc + c[b] - 99999.0f * mask[wid];
}

// ---------------------------------------------------------------------------
// Kernel 4: softmax over the S axis, per b. One block per b (B=32 blocks).
// Stages the 4096 scores for this b in LDS; writes distribution [S,B].
// ---------------------------------------------------------------------------
__global__ void softmax_kernel(const float* __restrict__ scores,
                               float* __restrict__ dist) {
    const int b = blockIdx.x;
    const int t = threadIdx.x;  // 256 threads
    __shared__ float sm[S];
    __shared__ float red[256];

    float m = -1e30f;
    for (int s = t; s < S; s += 256) {
        float x = scores[s * B + b];
        sm[s] = x;
        m = fmaxf(m, x);
    }
    red[t] = m;
    __syncthreads();
    for (int off = 128; off; off >>= 1) {
        if (t < off) red[t] = fmaxf(red[t], red[t + off]);
        __syncthreads();
    }
    m = red[0];
    __syncthreads();

    float sum = 0.f;
    for (int s = t; s < S; s += 256) {
        float e = expf(sm[s] - m);
        sm[s] = e;
        sum += e;
    }
    red[t] = sum;
    __syncthreads();
    for (int off = 128; off; off >>= 1) {
        if (t < off) red[t] += red[t + off];
        __syncthreads();
    }
    const float inv = 1.f / red[0];

    for (int s = t; s < S; s += 256)
        dist[s * B + b] = sm[s] * inv;
}

// ---------------------------------------------------------------------------
// Kernel 5: summary[b,f] = sum_s features[s,b,f] * dist[s,b]
// Grid (B, S/128); block 512 (thread = f). Partial over a 128-row s-chunk,
// then one atomicAdd per (thread, block) into the zeroed summary.
// ---------------------------------------------------------------------------
constexpr int POOL_CHUNK = 128;

__global__ void pool_kernel(const float* __restrict__ features,
                            const float* __restrict__ dist,
                            float* __restrict__ summary) {
    const int b = blockIdx.x;
    const int chunk = blockIdx.y;
    const int f = threadIdx.x;  // 512
    const int s0 = chunk * POOL_CHUNK;

    float acc = 0.f;
    for (int s = s0; s < s0 + POOL_CHUNK; ++s) {
        const float w = dist[s * B + b];
        acc = fmaf(w, features[((size_t)s * B + b) * F + f], acc);
    }
    atomicAdd(&summary[b * F + f], acc);
}

// ---------------------------------------------------------------------------
extern "C" void kernel_launch(void* const* d_in, const int* in_sizes, int n_in,
                              void* d_out, int out_size, void* d_ws, size_t ws_size,
                              hipStream_t stream) {
    const float* features = (const float*)d_in[0];  // [S,B,F]
    const float* hidden   = (const float*)d_in[1];  // [1,B,H]
    const float* mask     = (const float*)d_in[2];  // [S,B]
    const float* W_key    = (const float*)d_in[3];  // [H,F]
    const float* b_key    = (const float*)d_in[4];  // [H]

    float* out     = (float*)d_out;
    float* summary = out;          // [1,B,F] = 16384 floats
    float* dist    = out + B * F;  // [S,B]   = 131072 floats

    float* v      = (float*)d_ws;   // B*F floats
    float* c      = v + B * F;      // B floats
    float* scores = c + 32;         // S*B floats (offset 65664 B, 16-aligned)

    // summary is accumulated with atomics -> zero it (d_out is poisoned 0xAA)
    hipMemsetAsync(summary, 0, B * F * sizeof(float), stream);

    proj_kernel<<<dim3(F / 64, B), 64, 0, stream>>>(hidden, W_key, v);
    bias_dot_kernel<<<B, 64, 0, stream>>>(hidden, b_key, c);
    score_kernel<<<(S * B) / 4, 256, 0, stream>>>(features, mask, v, c, scores);
    softmax_kernel<<<B, 256, 0, stream>>>(scores, dist);
    pool_kernel<<<dim3(B, S / POOL_CHUNK), 512, 0, stream>>>(features, dist, summary);
}

// Round 3
// 413.037 us; speedup vs baseline: 1.0929x; 1.0929x over previous
//
#include <hip/hip_runtime.h>

// Problem constants: S=4096, B=32, F=512, H=512
constexpr int S = 4096;
constexpr int B = 32;
constexpr int F = 512;
constexpr int H = 512;

constexpr int RPW    = 32;        // rows (s-positions) per wave
constexpr int CHUNKS = S / RPW;   // 128 chunks per b
constexpr int WPB    = 4;         // waves per block

// ---------------------------------------------------------------------------
// Kernel 1: v[b,f] = sum_h hidden[b,h] * W_key[h,f]   (W_key 1MB, L2-resident)
// ---------------------------------------------------------------------------
__global__ void proj_kernel(const float* __restrict__ hidden,
                            const float* __restrict__ W_key,
                            float* __restrict__ v) {
    const int b = blockIdx.y;
    const int f = blockIdx.x * 64 + threadIdx.x;
    const float* hb = hidden + b * H;
    float acc = 0.f;
#pragma unroll 8
    for (int h = 0; h < H; ++h)
        acc = fmaf(hb[h], W_key[h * F + f], acc);
    v[b * F + f] = acc;
}

// ---------------------------------------------------------------------------
// Kernel 2: c[b] = <b_key, hidden[b,:]>  (one wave per b)
// ---------------------------------------------------------------------------
__global__ void bias_dot_kernel(const float* __restrict__ hidden,
                                const float* __restrict__ b_key,
                                float* __restrict__ c) {
    const int b = blockIdx.x;
    const int lane = threadIdx.x;  // 64
    float acc = 0.f;
    for (int h = lane; h < H; h += 64)
        acc = fmaf(b_key[h], hidden[b * H + h], acc);
    for (int off = 32; off; off >>= 1) acc += __shfl_down(acc, off);
    if (lane == 0) c[b] = acc;
}

// ---------------------------------------------------------------------------
// Kernel 3 (FUSED, single pass over features):
// per wave = one (b, 32-row chunk): score each row (dot with v[b] via
// shfl_xor butterfly), write raw score, and online-softmax-accumulate the
// unnormalized weighted row into registers. Emit per-chunk partials.
// ---------------------------------------------------------------------------
__global__ __launch_bounds__(WPB * 64) void fused_score_pool(
    const float* __restrict__ features,  // [S,B,F]
    const float* __restrict__ mask,      // [S,B]
    const float* __restrict__ v,         // [B,F]
    const float* __restrict__ c,         // [B]
    float* __restrict__ scores,          // [S,B]
    float* __restrict__ pacc,            // [B][CHUNKS][F]
    float* __restrict__ pm,              // [B][CHUNKS]
    float* __restrict__ pl) {            // [B][CHUNKS]
    const int lane  = threadIdx.x & 63;
    const int b     = blockIdx.x & (B - 1);
    const int chunk = (blockIdx.x >> 5) * WPB + (threadIdx.x >> 6);  // 0..127
    const int s0    = chunk * RPW;

    const float4* vb = reinterpret_cast<const float4*>(v + b * F);
    const float4 v0 = vb[lane];
    const float4 v1 = vb[lane + 64];
    const float cb = c[b];

    float m = -3.0e38f, l = 0.f;
    float4 a0 = make_float4(0.f, 0.f, 0.f, 0.f);
    float4 a1 = make_float4(0.f, 0.f, 0.f, 0.f);

    // prefetch row 0
    const float4* row = reinterpret_cast<const float4*>(
        features + ((size_t)s0 * B + b) * F);
    float4 r0 = row[lane];
    float4 r1 = row[lane + 64];
    float mk = mask[s0 * B + b];

    for (int i = 0; i < RPW; ++i) {
        // prefetch next row (clamped; last iteration re-loads same row, L1-hot)
        const int sn = s0 + ((i + 1 < RPW) ? i + 1 : i);
        const float4* nrow = reinterpret_cast<const float4*>(
            features + ((size_t)sn * B + b) * F);
        float4 n0 = nrow[lane];
        float4 n1 = nrow[lane + 64];
        float nmk = mask[sn * B + b];

        float dot = r0.x * v0.x + r0.y * v0.y + r0.z * v0.z + r0.w * v0.w
                  + r1.x * v1.x + r1.y * v1.y + r1.z * v1.z + r1.w * v1.w;
#pragma unroll
        for (int off = 32; off; off >>= 1) dot += __shfl_xor(dot, off);

        const float score = dot + cb - 99999.0f * mk;
        if (lane == 0) scores[(s0 + i) * B + b] = score;

        if (score > m) {                    // wave-uniform, rare after warm-up
            const float sc = __expf(m - score);   // first iter: exp(-inf)=0
            a0.x = fmaf(a0.x, sc, r0.x);
            a0.y = fmaf(a0.y, sc, r0.y);
            a0.z = fmaf(a0.z, sc, r0.z);
            a0.w = fmaf(a0.w, sc, r0.w);
            a1.x = fmaf(a1.x, sc, r1.x);
            a1.y = fmaf(a1.y, sc, r1.y);
            a1.z = fmaf(a1.z, sc, r1.z);
            a1.w = fmaf(a1.w, sc, r1.w);
            l = fmaf(l, sc, 1.f);
            m = score;
        } else {
            const float w = __expf(score - m);
            a0.x = fmaf(w, r0.x, a0.x);
            a0.y = fmaf(w, r0.y, a0.y);
            a0.z = fmaf(w, r0.z, a0.z);
            a0.w = fmaf(w, r0.w, a0.w);
            a1.x = fmaf(w, r1.x, a1.x);
            a1.y = fmaf(w, r1.y, a1.y);
            a1.z = fmaf(w, r1.z, a1.z);
            a1.w = fmaf(w, r1.w, a1.w);
            l += w;
        }
        r0 = n0; r1 = n1; mk = nmk;
    }

    float4* pa = reinterpret_cast<float4*>(pacc + ((size_t)b * CHUNKS + chunk) * F);
    pa[lane]      = a0;
    pa[lane + 64] = a1;
    if (lane == 0) {
        pm[b * CHUNKS + chunk] = m;
        pl[b * CHUNKS + chunk] = l;
    }
}

// ---------------------------------------------------------------------------
// Kernel 4: per-b combine of chunk (m,l) -> global M[b], 1/L[b]
// ---------------------------------------------------------------------------
__global__ void combine_kernel(const float* __restrict__ pm,
                               const float* __restrict__ pl,
                               float* __restrict__ Mb,
                               float* __restrict__ invLb) {
    const int b = blockIdx.x;
    const int t = threadIdx.x;  // CHUNKS = 128
    __shared__ float sm[CHUNKS];
    __shared__ float sl[CHUNKS];

    const float mv = pm[b * CHUNKS + t];
    sm[t] = mv;
    __syncthreads();
    for (int off = CHUNKS / 2; off; off >>= 1) {
        if (t < off) sm[t] = fmaxf(sm[t], sm[t + off]);
        __syncthreads();
    }
    const float M = sm[0];
    __syncthreads();

    sl[t] = pl[b * CHUNKS + t] * __expf(mv - M);
    __syncthreads();
    for (int off = CHUNKS / 2; off; off >>= 1) {
        if (t < off) sl[t] += sl[t + off];
        __syncthreads();
    }
    if (t == 0) {
        Mb[b] = M;
        invLb[b] = 1.f / sl[0];
    }
}

// ---------------------------------------------------------------------------
// Kernel 5: dist[s,b] = exp(scores[s,b] - M[b]) / L[b]
// ---------------------------------------------------------------------------
__global__ void dist_kernel(const float* __restrict__ scores,
                            const float* __restrict__ Mb,
                            const float* __restrict__ invLb,
                            float* __restrict__ dist) {
    const int i = blockIdx.x * blockDim.x + threadIdx.x;  // S*B threads
    const int b = i & (B - 1);
    dist[i] = __expf(scores[i] - Mb[b]) * invLb[b];
}

// ---------------------------------------------------------------------------
// Kernel 6: summary[b,f] = sum_c exp(pm[b,c]-M[b])/L[b] * pacc[b,c,f]
// grid (B, 4): each block handles 32 chunks, atomicAdd into zeroed summary.
// ---------------------------------------------------------------------------
constexpr int QCH = CHUNKS / 4;  // 32 chunks per block

__global__ __launch_bounds__(F) void summary_kernel(
    const float* __restrict__ pacc,
    const float* __restrict__ pm,
    const float* __restrict__ Mb,
    const float* __restrict__ invLb,
    float* __restrict__ summary) {
    const int b = blockIdx.x;
    const int q = blockIdx.y;
    const int f = threadIdx.x;  // 512
    const float M = Mb[b];
    const float invL = invLb[b];

    float acc = 0.f;
#pragma unroll 4
    for (int j = 0; j < QCH; ++j) {
        const int cidx = q * QCH + j;
        const float coef = __expf(pm[b * CHUNKS + cidx] - M) * invL;
        acc = fmaf(coef, pacc[((size_t)b * CHUNKS + cidx) * F + f], acc);
    }
    atomicAdd(&summary[b * F + f], acc);
}

// ---------------------------------------------------------------------------
extern "C" void kernel_launch(void* const* d_in, const int* in_sizes, int n_in,
                              void* d_out, int out_size, void* d_ws, size_t ws_size,
                              hipStream_t stream) {
    const float* features = (const float*)d_in[0];  // [S,B,F]
    const float* hidden   = (const float*)d_in[1];  // [1,B,H]
    const float* mask     = (const float*)d_in[2];  // [S,B]
    const float* W_key    = (const float*)d_in[3];  // [H,F]
    const float* b_key    = (const float*)d_in[4];  // [H]

    float* out     = (float*)d_out;
    float* summary = out;          // [1,B,F]
    float* dist    = out + B * F;  // [S,B]

    // workspace layout (floats); pacc first for 16B alignment
    float* ws     = (float*)d_ws;
    float* pacc   = ws;                               // B*CHUNKS*F = 2,097,152
    float* v      = pacc + (size_t)B * CHUNKS * F;    // 16384
    float* c      = v + B * F;                        // 32
    float* Mb     = c + B;                            // 32
    float* invLb  = Mb + B;                           // 32
    float* pm     = invLb + B;                        // B*CHUNKS = 4096
    float* pl     = pm + B * CHUNKS;                  // 4096
    float* scores = pl + B * CHUNKS;                  // S*B = 131072

    // summary is accumulated with atomics -> zero it (d_out poisoned 0xAA)
    hipMemsetAsync(summary, 0, B * F * sizeof(float), stream);

    proj_kernel<<<dim3(F / 64, B), 64, 0, stream>>>(hidden, W_key, v);
    bias_dot_kernel<<<B, 64, 0, stream>>>(hidden, b_key, c);

    fused_score_pool<<<B * CHUNKS / WPB, WPB * 64, 0, stream>>>(
        features, mask, v, c, scores, pacc, pm, pl);

    combine_kernel<<<B, CHUNKS, 0, stream>>>(pm, pl, Mb, invLb);
    dist_kernel<<<(S * B) / 256, 256, 0, stream>>>(scores, Mb, invLb, dist);
    summary_kernel<<<dim3(B, 4), F, 0, stream>>>(pacc, pm, Mb, invLb, summary);
}

// Round 4
// 408.006 us; speedup vs baseline: 1.1064x; 1.0123x over previous
//
#include <hip/hip_runtime.h>

// Problem constants: S=4096, B=32, F=512, H=512
constexpr int S = 4096;
constexpr int B = 32;
constexpr int F = 512;
constexpr int H = 512;

constexpr int RPW    = 32;        // rows (s-positions) per wave
constexpr int CHUNKS = S / RPW;   // 128 chunks per b
constexpr int WPB    = 4;         // waves per block

// ---------------------------------------------------------------------------
// Kernel 1 (prep): v[b,f] = sum_h hidden[b,h]*W_key[h,f];  zero summary[b,f];
// y==0 blocks additionally wave-reduce c[b] = <b_key, hidden[b,:]>.
// Grid (B, F/64) x 64 threads = 256 blocks -> full machine, 128KB reads each.
// ---------------------------------------------------------------------------
__global__ __launch_bounds__(64) void prep_kernel(
    const float* __restrict__ hidden,
    const float* __restrict__ W_key,
    const float* __restrict__ b_key,
    float* __restrict__ v,
    float* __restrict__ c,
    float* __restrict__ summary) {
    const int b    = blockIdx.x;
    const int lane = threadIdx.x;               // 64
    const int f    = blockIdx.y * 64 + lane;
    const float* hb = hidden + b * H;

    float acc = 0.f;
#pragma unroll 8
    for (int h = 0; h < H; ++h)
        acc = fmaf(hb[h], W_key[h * F + f], acc);
    v[b * F + f] = acc;
    summary[b * F + f] = 0.f;                   // d_out poisoned 0xAA -> zero it

    if (blockIdx.y == 0) {
        float ca = 0.f;
        for (int h = lane; h < H; h += 64)
            ca = fmaf(b_key[h], hb[h], ca);
#pragma unroll
        for (int off = 32; off; off >>= 1) ca += __shfl_down(ca, off);
        if (lane == 0) c[b] = ca;
    }
}

// ---------------------------------------------------------------------------
// Kernel 2 (FUSED, single pass over features):
// per wave = one (b, 32-row chunk): score each row (dot with v[b] via
// shfl_xor butterfly), write raw score, and online-softmax-accumulate the
// unnormalized weighted row into registers. Emit per-chunk partials.
// ---------------------------------------------------------------------------
__global__ __launch_bounds__(WPB * 64) void fused_score_pool(
    const float* __restrict__ features,  // [S,B,F]
    const float* __restrict__ mask,      // [S,B]
    const float* __restrict__ v,         // [B,F]
    const float* __restrict__ c,         // [B]
    float* __restrict__ scores,          // [S,B]
    float* __restrict__ pacc,            // [B][CHUNKS][F]
    float* __restrict__ pm,              // [B][CHUNKS]
    float* __restrict__ pl) {            // [B][CHUNKS]
    const int lane  = threadIdx.x & 63;
    const int b     = blockIdx.x & (B - 1);
    const int chunk = (blockIdx.x >> 5) * WPB + (threadIdx.x >> 6);  // 0..127
    const int s0    = chunk * RPW;

    const float4* vb = reinterpret_cast<const float4*>(v + b * F);
    const float4 v0 = vb[lane];
    const float4 v1 = vb[lane + 64];
    const float cb = c[b];

    float m = -3.0e38f, l = 0.f;
    float4 a0 = make_float4(0.f, 0.f, 0.f, 0.f);
    float4 a1 = make_float4(0.f, 0.f, 0.f, 0.f);

    // prefetch row 0
    const float4* row = reinterpret_cast<const float4*>(
        features + ((size_t)s0 * B + b) * F);
    float4 r0 = row[lane];
    float4 r1 = row[lane + 64];
    float mk = mask[s0 * B + b];

    for (int i = 0; i < RPW; ++i) {
        // prefetch next row (clamped; last iteration re-loads same row, L1-hot)
        const int sn = s0 + ((i + 1 < RPW) ? i + 1 : i);
        const float4* nrow = reinterpret_cast<const float4*>(
            features + ((size_t)sn * B + b) * F);
        float4 n0 = nrow[lane];
        float4 n1 = nrow[lane + 64];
        float nmk = mask[sn * B + b];

        float dot = r0.x * v0.x + r0.y * v0.y + r0.z * v0.z + r0.w * v0.w
                  + r1.x * v1.x + r1.y * v1.y + r1.z * v1.z + r1.w * v1.w;
#pragma unroll
        for (int off = 32; off; off >>= 1) dot += __shfl_xor(dot, off);

        const float score = dot + cb - 99999.0f * mk;
        if (lane == 0) scores[(s0 + i) * B + b] = score;

        if (score > m) {                    // wave-uniform, rare after warm-up
            const float sc = __expf(m - score);   // first iter: exp(-inf)=0
            a0.x = fmaf(a0.x, sc, r0.x);
            a0.y = fmaf(a0.y, sc, r0.y);
            a0.z = fmaf(a0.z, sc, r0.z);
            a0.w = fmaf(a0.w, sc, r0.w);
            a1.x = fmaf(a1.x, sc, r1.x);
            a1.y = fmaf(a1.y, sc, r1.y);
            a1.z = fmaf(a1.z, sc, r1.z);
            a1.w = fmaf(a1.w, sc, r1.w);
            l = fmaf(l, sc, 1.f);
            m = score;
        } else {
            const float w = __expf(score - m);
            a0.x = fmaf(w, r0.x, a0.x);
            a0.y = fmaf(w, r0.y, a0.y);
            a0.z = fmaf(w, r0.z, a0.z);
            a0.w = fmaf(w, r0.w, a0.w);
            a1.x = fmaf(w, r1.x, a1.x);
            a1.y = fmaf(w, r1.y, a1.y);
            a1.z = fmaf(w, r1.z, a1.z);
            a1.w = fmaf(w, r1.w, a1.w);
            l += w;
        }
        r0 = n0; r1 = n1; mk = nmk;
    }

    float4* pa = reinterpret_cast<float4*>(pacc + ((size_t)b * CHUNKS + chunk) * F);
    pa[lane]      = a0;
    pa[lane + 64] = a1;
    if (lane == 0) {
        pm[b * CHUNKS + chunk] = m;
        pl[b * CHUNKS + chunk] = l;
    }
}

// ---------------------------------------------------------------------------
// Kernel 3: per-b combine of chunk (m,l) -> global M[b], 1/L[b]
// ---------------------------------------------------------------------------
__global__ void combine_kernel(const float* __restrict__ pm,
                               const float* __restrict__ pl,
                               float* __restrict__ Mb,
                               float* __restrict__ invLb) {
    const int b = blockIdx.x;
    const int t = threadIdx.x;  // CHUNKS = 128
    __shared__ float sm[CHUNKS];
    __shared__ float sl[CHUNKS];

    const float mv = pm[b * CHUNKS + t];
    sm[t] = mv;
    __syncthreads();
    for (int off = CHUNKS / 2; off; off >>= 1) {
        if (t < off) sm[t] = fmaxf(sm[t], sm[t + off]);
        __syncthreads();
    }
    const float M = sm[0];
    __syncthreads();

    sl[t] = pl[b * CHUNKS + t] * __expf(mv - M);
    __syncthreads();
    for (int off = CHUNKS / 2; off; off >>= 1) {
        if (t < off) sl[t] += sl[t + off];
        __syncthreads();
    }
    if (t == 0) {
        Mb[b] = M;
        invLb[b] = 1.f / sl[0];
    }
}

// ---------------------------------------------------------------------------
// Kernel 4: dist[s,b] = exp(scores[s,b] - M[b]) / L[b]   (fully coalesced)
// ---------------------------------------------------------------------------
__global__ void dist_kernel(const float* __restrict__ scores,
                            const float* __restrict__ Mb,
                            const float* __restrict__ invLb,
                            float* __restrict__ dist) {
    const int i = blockIdx.x * blockDim.x + threadIdx.x;  // S*B threads
    const int b = i & (B - 1);
    dist[i] = __expf(scores[i] - Mb[b]) * invLb[b];
}

// ---------------------------------------------------------------------------
// Kernel 5: summary[b,f] = sum_c exp(pm[b,c]-M[b])/L[b] * pacc[b,c,f]
// grid (B, 4): each block handles 32 chunks, atomicAdd into zeroed summary.
// (summary zeroed by prep_kernel earlier on the same stream.)
// ---------------------------------------------------------------------------
constexpr int QCH = CHUNKS / 4;  // 32 chunks per block

__global__ __launch_bounds__(F) void summary_kernel(
    const float* __restrict__ pacc,
    const float* __restrict__ pm,
    const float* __restrict__ Mb,
    const float* __restrict__ invLb,
    float* __restrict__ summary) {
    const int b = blockIdx.x;
    const int q = blockIdx.y;
    const int f = threadIdx.x;  // 512
    const float M = Mb[b];
    const float invL = invLb[b];

    float acc = 0.f;
#pragma unroll 4
    for (int j = 0; j < QCH; ++j) {
        const int cidx = q * QCH + j;
        const float coef = __expf(pm[b * CHUNKS + cidx] - M) * invL;
        acc = fmaf(coef, pacc[((size_t)b * CHUNKS + cidx) * F + f], acc);
    }
    atomicAdd(&summary[b * F + f], acc);
}

// ---------------------------------------------------------------------------
extern "C" void kernel_launch(void* const* d_in, const int* in_sizes, int n_in,
                              void* d_out, int out_size, void* d_ws, size_t ws_size,
                              hipStream_t stream) {
    const float* features = (const float*)d_in[0];  // [S,B,F]
    const float* hidden   = (const float*)d_in[1];  // [1,B,H]
    const float* mask     = (const float*)d_in[2];  // [S,B]
    const float* W_key    = (const float*)d_in[3];  // [H,F]
    const float* b_key    = (const float*)d_in[4];  // [H]

    float* out     = (float*)d_out;
    float* summary = out;          // [1,B,F]
    float* dist    = out + B * F;  // [S,B]

    // workspace layout (floats); pacc first for 16B alignment
    float* ws     = (float*)d_ws;
    float* pacc   = ws;                               // B*CHUNKS*F = 2,097,152
    float* v      = pacc + (size_t)B * CHUNKS * F;    // 16384
    float* c      = v + B * F;                        // 32
    float* Mb     = c + B;                            // 32
    float* invLb  = Mb + B;                           // 32
    float* pm     = invLb + B;                        // B*CHUNKS = 4096
    float* pl     = pm + B * CHUNKS;                  // 4096
    float* scores = pl + B * CHUNKS;                  // S*B = 131072

    prep_kernel<<<dim3(B, F / 64), 64, 0, stream>>>(
        hidden, W_key, b_key, v, c, summary);

    fused_score_pool<<<B * CHUNKS / WPB, WPB * 64, 0, stream>>>(
        features, mask, v, c, scores, pacc, pm, pl);

    combine_kernel<<<B, CHUNKS, 0, stream>>>(pm, pl, Mb, invLb);
    dist_kernel<<<(S * B) / 256, 256, 0, stream>>>(scores, Mb, invLb, dist);
    summary_kernel<<<dim3(B, 4), F, 0, stream>>>(pacc, pm, Mb, invLb, summary);
}

// Round 5
// 406.897 us; speedup vs baseline: 1.1094x; 1.0027x over previous
//
#include <hip/hip_runtime.h>

// Problem constants: S=4096, B=32, F=512, H=512
constexpr int S = 4096;
constexpr int B = 32;
constexpr int F = 512;
constexpr int H = 512;

constexpr int RPW    = 32;        // rows (s-positions) per wave
constexpr int CHUNKS = S / RPW;   // 128 chunks per b
constexpr int WPB    = 4;         // waves per block

// ---------------------------------------------------------------------------
// Kernel 1 (prep): v[b,f] = sum_h hidden[b,h]*W_key[h,f];  zero summary[b,f];
// y==0 blocks additionally wave-reduce c[b] = <b_key, hidden[b,:]>.
// ---------------------------------------------------------------------------
__global__ __launch_bounds__(64) void prep_kernel(
    const float* __restrict__ hidden,
    const float* __restrict__ W_key,
    const float* __restrict__ b_key,
    float* __restrict__ v,
    float* __restrict__ c,
    float* __restrict__ summary) {
    const int b    = blockIdx.x;
    const int lane = threadIdx.x;               // 64
    const int f    = blockIdx.y * 64 + lane;
    const float* hb = hidden + b * H;

    float acc = 0.f;
#pragma unroll 8
    for (int h = 0; h < H; ++h)
        acc = fmaf(hb[h], W_key[h * F + f], acc);
    v[b * F + f] = acc;
    summary[b * F + f] = 0.f;                   // d_out poisoned 0xAA -> zero it

    if (blockIdx.y == 0) {
        float ca = 0.f;
        for (int h = lane; h < H; h += 64)
            ca = fmaf(b_key[h], hb[h], ca);
#pragma unroll
        for (int off = 32; off; off >>= 1) ca += __shfl_down(ca, off);
        if (lane == 0) c[b] = ca;
    }
}

// ---------------------------------------------------------------------------
// Kernel 2 (FUSED, single pass over features):
// per wave = one (b, 32-row chunk): score each row (dot with v[b] via
// shfl_xor butterfly), write raw score, and online-softmax-accumulate the
// unnormalized weighted row into registers. Emit per-chunk partials.
// ---------------------------------------------------------------------------
__global__ __launch_bounds__(WPB * 64) void fused_score_pool(
    const float* __restrict__ features,  // [S,B,F]
    const float* __restrict__ mask,      // [S,B]
    const float* __restrict__ v,         // [B,F]
    const float* __restrict__ c,         // [B]
    float* __restrict__ scores,          // [S,B]
    float* __restrict__ pacc,            // [B][CHUNKS][F]
    float* __restrict__ pm,              // [B][CHUNKS]
    float* __restrict__ pl) {            // [B][CHUNKS]
    const int lane  = threadIdx.x & 63;
    const int b     = blockIdx.x & (B - 1);
    const int chunk = (blockIdx.x >> 5) * WPB + (threadIdx.x >> 6);  // 0..127
    const int s0    = chunk * RPW;

    const float4* vb = reinterpret_cast<const float4*>(v + b * F);
    const float4 v0 = vb[lane];
    const float4 v1 = vb[lane + 64];
    const float cb = c[b];

    float m = -3.0e38f, l = 0.f;
    float4 a0 = make_float4(0.f, 0.f, 0.f, 0.f);
    float4 a1 = make_float4(0.f, 0.f, 0.f, 0.f);

    // prefetch row 0
    const float4* row = reinterpret_cast<const float4*>(
        features + ((size_t)s0 * B + b) * F);
    float4 r0 = row[lane];
    float4 r1 = row[lane + 64];
    float mk = mask[s0 * B + b];

    for (int i = 0; i < RPW; ++i) {
        // prefetch next row (clamped; last iteration re-loads same row, L1-hot)
        const int sn = s0 + ((i + 1 < RPW) ? i + 1 : i);
        const float4* nrow = reinterpret_cast<const float4*>(
            features + ((size_t)sn * B + b) * F);
        float4 n0 = nrow[lane];
        float4 n1 = nrow[lane + 64];
        float nmk = mask[sn * B + b];

        float dot = r0.x * v0.x + r0.y * v0.y + r0.z * v0.z + r0.w * v0.w
                  + r1.x * v1.x + r1.y * v1.y + r1.z * v1.z + r1.w * v1.w;
#pragma unroll
        for (int off = 32; off; off >>= 1) dot += __shfl_xor(dot, off);

        const float score = dot + cb - 99999.0f * mk;
        if (lane == 0) scores[(s0 + i) * B + b] = score;

        if (score > m) {                    // wave-uniform, rare after warm-up
            const float sc = __expf(m - score);   // first iter: exp(-inf)=0
            a0.x = fmaf(a0.x, sc, r0.x);
            a0.y = fmaf(a0.y, sc, r0.y);
            a0.z = fmaf(a0.z, sc, r0.z);
            a0.w = fmaf(a0.w, sc, r0.w);
            a1.x = fmaf(a1.x, sc, r1.x);
            a1.y = fmaf(a1.y, sc, r1.y);
            a1.z = fmaf(a1.z, sc, r1.z);
            a1.w = fmaf(a1.w, sc, r1.w);
            l = fmaf(l, sc, 1.f);
            m = score;
        } else {
            const float w = __expf(score - m);
            a0.x = fmaf(w, r0.x, a0.x);
            a0.y = fmaf(w, r0.y, a0.y);
            a0.z = fmaf(w, r0.z, a0.z);
            a0.w = fmaf(w, r0.w, a0.w);
            a1.x = fmaf(w, r1.x, a1.x);
            a1.y = fmaf(w, r1.y, a1.y);
            a1.z = fmaf(w, r1.z, a1.z);
            a1.w = fmaf(w, r1.w, a1.w);
            l += w;
        }
        r0 = n0; r1 = n1; mk = nmk;
    }

    float4* pa = reinterpret_cast<float4*>(pacc + ((size_t)b * CHUNKS + chunk) * F);
    pa[lane]      = a0;
    pa[lane + 64] = a1;
    if (lane == 0) {
        pm[b * CHUNKS + chunk] = m;
        pl[b * CHUNKS + chunk] = l;
    }
}

// ---------------------------------------------------------------------------
// Kernel 3: per-b combine of chunk (m,l) -> global M[b], 1/L[b]
// ---------------------------------------------------------------------------
__global__ void combine_kernel(const float* __restrict__ pm,
                               const float* __restrict__ pl,
                               float* __restrict__ Mb,
                               float* __restrict__ invLb) {
    const int b = blockIdx.x;
    const int t = threadIdx.x;  // CHUNKS = 128
    __shared__ float sm[CHUNKS];
    __shared__ float sl[CHUNKS];

    const float mv = pm[b * CHUNKS + t];
    sm[t] = mv;
    __syncthreads();
    for (int off = CHUNKS / 2; off; off >>= 1) {
        if (t < off) sm[t] = fmaxf(sm[t], sm[t + off]);
        __syncthreads();
    }
    const float M = sm[0];
    __syncthreads();

    sl[t] = pl[b * CHUNKS + t] * __expf(mv - M);
    __syncthreads();
    for (int off = CHUNKS / 2; off; off >>= 1) {
        if (t < off) sl[t] += sl[t + off];
        __syncthreads();
    }
    if (t == 0) {
        Mb[b] = M;
        invLb[b] = 1.f / sl[0];
    }
}

// ---------------------------------------------------------------------------
// Kernel 4 (finalize): block-role split.
//   blocks [0, B*4):      summary[b,f] += sum over 32 chunks (atomicAdd)
//   blocks [B*4, B*4+64): dist (float4-vectorized, fully coalesced)
// ---------------------------------------------------------------------------
constexpr int QCH = CHUNKS / 4;            // 32 chunks per summary block
constexpr int DIST_V4 = (S * B) / 4;       // 32768 float4 elements
constexpr int DIST_BLOCKS = DIST_V4 / 512; // 64

__global__ __launch_bounds__(512) void finalize_kernel(
    const float* __restrict__ scores,
    const float* __restrict__ pacc,
    const float* __restrict__ pm,
    const float* __restrict__ Mb,
    const float* __restrict__ invLb,
    float* __restrict__ dist,
    float* __restrict__ summary) {
    const int bid = blockIdx.x;
    const int t   = threadIdx.x;  // 512

    if (bid < B * 4) {
        // ---- summary role ----
        const int b = bid >> 2;
        const int q = bid & 3;
        const float M = Mb[b];
        const float invL = invLb[b];

        float acc = 0.f;
#pragma unroll 4
        for (int j = 0; j < QCH; ++j) {
            const int cidx = q * QCH + j;
            const float coef = __expf(pm[b * CHUNKS + cidx] - M) * invL;
            acc = fmaf(coef, pacc[((size_t)b * CHUNKS + cidx) * F + t], acc);
        }
        atomicAdd(&summary[b * F + t], acc);
    } else {
        // ---- dist role: j indexes float4s over the flat [S,B] array ----
        const int j = (bid - B * 4) * 512 + t;  // 0 .. DIST_V4-1
        const float4 sc = reinterpret_cast<const float4*>(scores)[j];
        const int b0 = (4 * j) & (B - 1);       // 4 consecutive b, 16B-aligned
        const float4 M4 = *reinterpret_cast<const float4*>(Mb + b0);
        const float4 L4 = *reinterpret_cast<const float4*>(invLb + b0);
        float4 d;
        d.x = __expf(sc.x - M4.x) * L4.x;
        d.y = __expf(sc.y - M4.y) * L4.y;
        d.z = __expf(sc.z - M4.z) * L4.z;
        d.w = __expf(sc.w - M4.w) * L4.w;
        reinterpret_cast<float4*>(dist)[j] = d;
    }
}

// ---------------------------------------------------------------------------
extern "C" void kernel_launch(void* const* d_in, const int* in_sizes, int n_in,
                              void* d_out, int out_size, void* d_ws, size_t ws_size,
                              hipStream_t stream) {
    const float* features = (const float*)d_in[0];  // [S,B,F]
    const float* hidden   = (const float*)d_in[1];  // [1,B,H]
    const float* mask     = (const float*)d_in[2];  // [S,B]
    const float* W_key    = (const float*)d_in[3];  // [H,F]
    const float* b_key    = (const float*)d_in[4];  // [H]

    float* out     = (float*)d_out;
    float* summary = out;          // [1,B,F]
    float* dist    = out + B * F;  // [S,B]

    // workspace layout (floats); pacc first for 16B alignment
    float* ws     = (float*)d_ws;
    float* pacc   = ws;                               // B*CHUNKS*F = 2,097,152
    float* v      = pacc + (size_t)B * CHUNKS * F;    // 16384
    float* c      = v + B * F;                        // 32
    float* Mb     = c + B;                            // 32  (16B-aligned)
    float* invLb  = Mb + B;                           // 32  (16B-aligned)
    float* pm     = invLb + B;                        // B*CHUNKS = 4096
    float* pl     = pm + B * CHUNKS;                  // 4096
    float* scores = pl + B * CHUNKS;                  // S*B = 131072

    prep_kernel<<<dim3(B, F / 64), 64, 0, stream>>>(
        hidden, W_key, b_key, v, c, summary);

    fused_score_pool<<<B * CHUNKS / WPB, WPB * 64, 0, stream>>>(
        features, mask, v, c, scores, pacc, pm, pl);

    combine_kernel<<<B, CHUNKS, 0, stream>>>(pm, pl, Mb, invLb);

    finalize_kernel<<<B * 4 + DIST_BLOCKS, 512, 0, stream>>>(
        scores, pacc, pm, Mb, invLb, dist, summary);
}